// Round 14
// baseline (459.921 us; speedup 1.0000x reference)
//
#include <hip/hip_runtime.h>
#include <cstddef>

#define NN 20000
#define EE 100000
#define NR 6
#define HH 2
#define NEG 0.2f

struct EdgePtrs { const int* e[NR]; };

typedef __attribute__((ext_vector_type(8))) short bf16x8;
typedef __attribute__((ext_vector_type(4))) float f32x4;

__device__ __forceinline__ unsigned short rnebf(float f) {
    unsigned u = __float_as_uint(f);
    return (unsigned short)((u + 0x7fffu + ((u >> 16) & 1u)) >> 16);
}
__device__ __forceinline__ void unpack8(uint4 v, float* f) {
    f[0] = __uint_as_float(v.x << 16); f[1] = __uint_as_float(v.x & 0xffff0000u);
    f[2] = __uint_as_float(v.y << 16); f[3] = __uint_as_float(v.y & 0xffff0000u);
    f[4] = __uint_as_float(v.z << 16); f[5] = __uint_as_float(v.z & 0xffff0000u);
    f[6] = __uint_as_float(v.w << 16); f[7] = __uint_as_float(v.w & 0xffff0000u);
}
__device__ __forceinline__ unsigned pack2(float a, float b) {
    return (unsigned)rnebf(a) | ((unsigned)rnebf(b) << 16);
}
__device__ __forceinline__ float lrelu(float l) { return l > 0.f ? l : NEG * l; }
__device__ __forceinline__ void glld16(unsigned short* lds, const void* g) {
    __builtin_amdgcn_global_load_lds(
        (const __attribute__((address_space(1))) unsigned int*)g,
        (__attribute__((address_space(3))) unsigned int*)lds, 16, 0, 0);
}

// fp32->bf16 of x, W1, W2  PLUS  CSR dst-histogram, one launch (block-role split)
__global__ void f2b_count(const float* __restrict__ x, unsigned short* __restrict__ xb, int nx,
                          const float* __restrict__ w1, unsigned short* __restrict__ wb1, int nw1,
                          const float* __restrict__ w2, unsigned short* __restrict__ wb2, int nw2,
                          int fb, EdgePtrs ep, int* __restrict__ count) {
    int b = blockIdx.x;
    if (b >= fb) {
        int i = (b - fb) * 256 + threadIdx.x;
        if (i < NR * EE) {
            int r = i / EE, ei = i - r * EE;
            atomicAdd(&count[ep.e[r][EE + ei]], 1);
        }
        return;
    }
    int i = (b * 256 + threadIdx.x) * 4;
    const float* in; unsigned short* out; int k;
    if (i < nx) { in = x; out = xb; k = i; }
    else if (i < nx + nw1) { in = w1; out = wb1; k = i - nx; }
    else if (i < nx + nw1 + nw2) { in = w2; out = wb2; k = i - nx - nw1; }
    else return;
    float4 v = *(const float4*)&in[k];
    unsigned short o[4] = {rnebf(v.x), rnebf(v.y), rnebf(v.z), rnebf(v.w)};
    *(uint2*)&out[k] = *(uint2*)o;
}

// all three attention-vector folds in one launch:
// z=0: wtd1 = fold(a1d, W1d)  C=512 K=512
// z=1: wts2 = fold(a2s, W2s)  C=128 K=1024
// z=2: wtd2 = fold(a2d, W2d)  C=128 K=1024
__global__ void fold_all(const float* __restrict__ W1d, const float* __restrict__ a1d,
                         float* __restrict__ wtd1,
                         const float* __restrict__ W2s, const float* __restrict__ a2s,
                         float* __restrict__ wts2,
                         const float* __restrict__ W2d, const float* __restrict__ a2d,
                         float* __restrict__ wtd2) {
    __shared__ float red[256];
    const float *W, *a; float* wt; int C, K;
    if (blockIdx.z == 0)      { W = W1d; a = a1d; wt = wtd1; C = 512; K = 512; }
    else if (blockIdx.z == 1) { W = W2s; a = a2s; wt = wts2; C = 128; K = 1024; }
    else                      { W = W2d; a = a2d; wt = wtd2; C = 128; K = 1024; }
    int h = blockIdx.y;
    int k = blockIdx.x * 64 + (threadIdx.x & 63);
    if (k >= K) return;   // block-uniform (K multiple of 64)
    int cp = threadIdx.x >> 6;
    float acc = 0.f;
    for (int c = cp; c < C; c += 4)
        acc = fmaf(a[h * C + c], W[(size_t)(h * C + c) * K + k], acc);
    red[threadIdx.x] = acc;
    __syncthreads();
    if (cp == 0) {
        wt[h * K + k] = red[threadIdx.x] + red[threadIdx.x + 64] +
                        red[threadIdx.x + 128] + red[threadIdx.x + 192];
    }
}

// C[M][Nn] = A[M][K] @ B[Nn][K]^T, bf16 in/out, fp32 accum (MFMA 16x16x32).
// FUSEAL: per-row dot of the OUTPUT with a1_src (al_src = xs . a_src).
template <int BN, bool FUSEAL>
__global__ __launch_bounds__(256) void gemm_nt_mfma(
    const unsigned short* __restrict__ A, const unsigned short* __restrict__ B,
    unsigned short* __restrict__ C, int M, int Nn, int K,
    const float* __restrict__ a1s, float* __restrict__ as1) {
    constexpr int NF = BN / 32;
    __shared__ unsigned short As[128 * 32];
    __shared__ unsigned short Bs[BN * 32];
    const int tid = threadIdx.x;
    const int lane = tid & 63;
    const int wave = tid >> 6;
    const int wr = wave >> 1, wc = wave & 1;
    const int row0 = blockIdx.y * 128, col0 = blockIdx.x * BN;

    f32x4 acc[4][NF];
#pragma unroll
    for (int i = 0; i < 4; ++i)
#pragma unroll
        for (int j = 0; j < NF; ++j) acc[i][j] = (f32x4){0.f, 0.f, 0.f, 0.f};

    const int srow = tid >> 2;
    const int slot = tid & 3;
    const int sw = ((slot ^ (srow & 3)) << 4);
    int ar0 = row0 + srow;        if (ar0 >= M) ar0 = M - 1;
    int ar1 = row0 + srow + 64;   if (ar1 >= M) ar1 = M - 1;
    const int br0 = col0 + srow;
    const int br1 = col0 + srow + 64;

    const int q = lane >> 4;
    for (int k0 = 0; k0 < K; k0 += 32) {
        glld16(As + tid * 8,        (const char*)A + ((size_t)ar0 * K + k0) * 2 + sw);
        glld16(As + tid * 8 + 2048, (const char*)A + ((size_t)ar1 * K + k0) * 2 + sw);
        glld16(Bs + tid * 8,        (const char*)B + ((size_t)br0 * K + k0) * 2 + sw);
        if (BN == 128)
            glld16(Bs + tid * 8 + 2048, (const char*)B + ((size_t)br1 * K + k0) * 2 + sw);
        __syncthreads();
        bf16x8 af[4], bfr[NF];
#pragma unroll
        for (int m = 0; m < 4; ++m) {
            int r = wr * 64 + m * 16 + (lane & 15);
            af[m] = *(const bf16x8*)&As[r * 32 + ((q ^ (r & 3)) << 3)];
        }
#pragma unroll
        for (int nI = 0; nI < NF; ++nI) {
            int c = wc * (BN / 2) + nI * 16 + (lane & 15);
            bfr[nI] = *(const bf16x8*)&Bs[c * 32 + ((q ^ (c & 3)) << 3)];
        }
#pragma unroll
        for (int m = 0; m < 4; ++m)
#pragma unroll
            for (int nI = 0; nI < NF; ++nI)
                acc[m][nI] = __builtin_amdgcn_mfma_f32_16x16x32_bf16(af[m], bfr[nI], acc[m][nI], 0, 0, 0);
        __syncthreads();
    }
    const int crow = (lane >> 4) * 4;
    const int ccol = lane & 15;
#pragma unroll
    for (int m = 0; m < 4; ++m)
#pragma unroll
        for (int nI = 0; nI < NF; ++nI)
#pragma unroll
            for (int j = 0; j < 4; ++j) {
                int r = row0 + wr * 64 + m * 16 + crow + j;
                int c = col0 + wc * (BN / 2) + nI * 16 + ccol;
                if (r < M) C[(size_t)r * Nn + c] = rnebf(acc[m][nI][j]);
            }
    if constexpr (FUSEAL) {
        const int hb = col0 >> 9;                   // C1 = 512
        float aS[NF];
#pragma unroll
        for (int nI = 0; nI < NF; ++nI) {
            int gc = col0 + wc * (BN / 2) + nI * 16 + ccol;
            aS[nI] = a1s[hb * 512 + (gc & 511)];
        }
#pragma unroll
        for (int m = 0; m < 4; ++m)
#pragma unroll
            for (int j = 0; j < 4; ++j) {
                float ps = 0.f;
#pragma unroll
                for (int nI = 0; nI < NF; ++nI)
                    ps = fmaf(acc[m][nI][j], aS[nI], ps);
                for (int o = 1; o < 16; o <<= 1)
                    ps += __shfl_xor(ps, o);
                if ((lane & 15) == 0) {
                    int r = row0 + wr * 64 + m * 16 + crow + j;
                    if (r < M) atomicAdd(&as1[r * 2 + hb], ps);
                }
            }
    }
}

// al_dst (wave-per-node) + single-block COALESCED tiled CSR scan, one launch.
__global__ void al_dst_scan(const unsigned short* __restrict__ x, const float* __restrict__ wtd,
                            int K, float* __restrict__ ad,
                            const int* __restrict__ count, int* __restrict__ offs,
                            int* __restrict__ cursor) {
    if (blockIdx.x == gridDim.x - 1) {
        // --- scan block: 256 threads, coalesced 256-wide tiles + carry ---
        __shared__ int wsum[4];
        __shared__ int carry;
        int tid = threadIdx.x;
        int lane = tid & 63, wid = tid >> 6;
        if (tid == 0) carry = 0;
        __syncthreads();
        for (int base = 0; base < NN; base += 256) {
            int idx = base + tid;
            int v = (idx < NN) ? count[idx] : 0;
            int xv = v;
            for (int d = 1; d < 64; d <<= 1) {
                int t2 = __shfl_up(xv, d);
                if (lane >= d) xv += t2;
            }
            if (lane == 63) wsum[wid] = xv;
            __syncthreads();
            int wb = 0;
            for (int w = 0; w < wid; ++w) wb += wsum[w];
            int excl = carry + wb + xv - v;
            if (idx < NN) { offs[idx] = excl; cursor[idx] = excl; }
            __syncthreads();
            if (tid == 255) carry += wb + xv;   // wb = waves 0..2, xv = wave3 total
            __syncthreads();
        }
        if (threadIdx.x == 0) offs[NN] = carry;
        return;
    }
    // --- al_dst blocks ---
    int lane = threadIdx.x & 63;
    int n = blockIdx.x * 4 + (threadIdx.x >> 6);
    if (n >= NN) return;
    float d0 = 0.f, d1 = 0.f;
    for (int k0 = 0; k0 < K; k0 += 512) {
        int k = k0 + lane * 8;
        uint4 xv = *(const uint4*)&x[(size_t)n * K + k];
        float xf[8];
        unpack8(xv, xf);
        float4 wda = *(const float4*)&wtd[k],     wdb = *(const float4*)&wtd[k + 4];
        float4 wdc = *(const float4*)&wtd[K + k], wdd = *(const float4*)&wtd[K + k + 4];
        d0 = fmaf(xf[0], wda.x, d0); d0 = fmaf(xf[1], wda.y, d0);
        d0 = fmaf(xf[2], wda.z, d0); d0 = fmaf(xf[3], wda.w, d0);
        d0 = fmaf(xf[4], wdb.x, d0); d0 = fmaf(xf[5], wdb.y, d0);
        d0 = fmaf(xf[6], wdb.z, d0); d0 = fmaf(xf[7], wdb.w, d0);
        d1 = fmaf(xf[0], wdc.x, d1); d1 = fmaf(xf[1], wdc.y, d1);
        d1 = fmaf(xf[2], wdc.z, d1); d1 = fmaf(xf[3], wdc.w, d1);
        d1 = fmaf(xf[4], wdd.x, d1); d1 = fmaf(xf[5], wdd.y, d1);
        d1 = fmaf(xf[6], wdd.z, d1); d1 = fmaf(xf[7], wdd.w, d1);
    }
    for (int o = 32; o > 0; o >>= 1) {
        d0 += __shfl_down(d0, o); d1 += __shfl_down(d1, o);
    }
    if (lane == 0) {
        ad[n * 2 + 0] = d0;
        ad[n * 2 + 1] = d1;
    }
}

// static CSR scatter (once): record = (src, relation)
__global__ void scatter_static(EdgePtrs ep, int* __restrict__ cursor, int2* __restrict__ recs) {
    int i = blockIdx.x * 256 + threadIdx.x;
    if (i >= NR * EE) return;
    int r = i / EE, ei = i - r * EE;
    int sN = ep.e[r][ei];
    int d = ep.e[r][EE + ei];
    int slot = atomicAdd(&cursor[d], 1);
    recs[slot] = make_int2(sN, r);
}

// L1 aggregate: in-block softmax denominators (LDS), inline-alpha,
// fused L2-al partial dots. 2 blocks/node (one per head), 64 thr x 8 ch.
__global__ __launch_bounds__(64) void aggregate_l1f(
    const unsigned short* __restrict__ xs, const int2* __restrict__ recs,
    const int* __restrict__ offs,
    const float* __restrict__ als, const float* __restrict__ ald,
    const float* __restrict__ bias,
    const float* __restrict__ wts2, const float* __restrict__ wtd2,
    float* __restrict__ as2, float* __restrict__ ad2,
    unsigned short* __restrict__ out) {
    __shared__ float s_loc[NR];
    int bid = blockIdx.x;
    int n = bid >> 1;
    int half = bid & 1;
    int t = threadIdx.x;
    int c0 = half * 512 + t * 8;
    float ad_n = ald[n * 2 + half];
    float els = expf(lrelu(als[n * 2 + half] + ad_n));  // self-loop term
    if (t < NR) s_loc[t] = els;
    __syncthreads();
    int beg = offs[n], end = offs[n + 1];
    for (int j = beg + t; j < end; j += 64) {
        int2 rc = recs[j];
        atomicAdd(&s_loc[rc.y], expf(lrelu(als[rc.x * 2 + half] + ad_n)));
    }
    __syncthreads();
    if (t < NR) s_loc[t] = 1.f / (s_loc[t] + 1e-16f);
    __syncthreads();
    float rsum = s_loc[0] + s_loc[1] + s_loc[2] + s_loc[3] + s_loc[4] + s_loc[5];
    float coef = els * rsum;
    float a0[8], a1[8], f[8];
    uint4 sv = *(const uint4*)&xs[(size_t)n * 1024 + c0];
    unpack8(sv, f);
#pragma unroll
    for (int j = 0; j < 8; ++j) {
        a0[j] = coef * f[j] + 6.f * bias[c0 + j];
        a1[j] = 0.f;
    }
    int j = beg;
    for (; j + 1 < end; j += 2) {
        int2 r0 = recs[j], r1 = recs[j + 1];
        uint4 v0 = *(const uint4*)&xs[(size_t)r0.x * 1024 + c0];
        uint4 v1 = *(const uint4*)&xs[(size_t)r1.x * 1024 + c0];
        float l0 = lrelu(als[r0.x * 2 + half] + ad_n);
        float l1 = lrelu(als[r1.x * 2 + half] + ad_n);
        float al0 = expf(l0) * s_loc[r0.y];
        float al1 = expf(l1) * s_loc[r1.y];
        unpack8(v0, f);
#pragma unroll
        for (int q = 0; q < 8; ++q) a0[q] = fmaf(al0, f[q], a0[q]);
        unpack8(v1, f);
#pragma unroll
        for (int q = 0; q < 8; ++q) a1[q] = fmaf(al1, f[q], a1[q]);
    }
    if (j < end) {
        int2 r0 = recs[j];
        uint4 v0 = *(const uint4*)&xs[(size_t)r0.x * 1024 + c0];
        float l0 = lrelu(als[r0.x * 2 + half] + ad_n);
        float al0 = expf(l0) * s_loc[r0.y];
        unpack8(v0, f);
#pragma unroll
        for (int q = 0; q < 8; ++q) a0[q] = fmaf(al0, f[q], a0[q]);
    }
    float rr[8];
#pragma unroll
    for (int q = 0; q < 8; ++q) rr[q] = fmaxf(a0[q] + a1[q], 0.f);
    uint4 o;
    o.x = pack2(rr[0], rr[1]); o.y = pack2(rr[2], rr[3]);
    o.z = pack2(rr[4], rr[5]); o.w = pack2(rr[6], rr[7]);
    *(uint4*)&out[(size_t)n * 1024 + c0] = o;
    // fused L2 attention-logit partial dots over this 8-channel slice
    float ps0, ps1, pd0, pd1;
    float4 wsa = *(const float4*)&wts2[c0],        wsb = *(const float4*)&wts2[c0 + 4];
    float4 wsc = *(const float4*)&wts2[1024 + c0], wsd = *(const float4*)&wts2[1024 + c0 + 4];
    float4 wda = *(const float4*)&wtd2[c0],        wdb = *(const float4*)&wtd2[c0 + 4];
    float4 wdc = *(const float4*)&wtd2[1024 + c0], wdd = *(const float4*)&wtd2[1024 + c0 + 4];
    ps0 = rr[0]*wsa.x + rr[1]*wsa.y + rr[2]*wsa.z + rr[3]*wsa.w
        + rr[4]*wsb.x + rr[5]*wsb.y + rr[6]*wsb.z + rr[7]*wsb.w;
    ps1 = rr[0]*wsc.x + rr[1]*wsc.y + rr[2]*wsc.z + rr[3]*wsc.w
        + rr[4]*wsd.x + rr[5]*wsd.y + rr[6]*wsd.z + rr[7]*wsd.w;
    pd0 = rr[0]*wda.x + rr[1]*wda.y + rr[2]*wda.z + rr[3]*wda.w
        + rr[4]*wdb.x + rr[5]*wdb.y + rr[6]*wdb.z + rr[7]*wdb.w;
    pd1 = rr[0]*wdc.x + rr[1]*wdc.y + rr[2]*wdc.z + rr[3]*wdc.w
        + rr[4]*wdd.x + rr[5]*wdd.y + rr[6]*wdd.z + rr[7]*wdd.w;
    for (int o2 = 32; o2 > 0; o2 >>= 1) {
        ps0 += __shfl_down(ps0, o2); ps1 += __shfl_down(ps1, o2);
        pd0 += __shfl_down(pd0, o2); pd1 += __shfl_down(pd1, o2);
    }
    if (t == 0) {
        atomicAdd(&as2[n * 2 + 0], ps0);
        atomicAdd(&as2[n * 2 + 1], ps1);
        atomicAdd(&ad2[n * 2 + 0], pd0);
        atomicAdd(&ad2[n * 2 + 1], pd1);
    }
}

// L2 aggregate: in-block denominators (both heads), inline-alpha. 64 thr x 4 ch.
__global__ __launch_bounds__(64) void aggregate_l2(
    const unsigned short* __restrict__ xs, const int2* __restrict__ recs,
    const int* __restrict__ offs,
    const float* __restrict__ als, const float* __restrict__ ald,
    const float* __restrict__ bias, float* __restrict__ out) {
    __shared__ float s_loc[NR * HH];   // [r][h]
    int n = blockIdx.x;
    int t = threadIdx.x;
    int h = t >> 5;
    float ad_n = ald[n * 2 + h];
    float els = expf(lrelu(als[n * 2 + h] + ad_n));
    if (t < NR * HH) s_loc[t] = expf(lrelu(als[n * 2 + (t & 1)] + ald[n * 2 + (t & 1)]));
    __syncthreads();
    int beg = offs[n], end = offs[n + 1];
    for (int j = beg + (t & 31); j < end; j += 32) {
        int2 rc = recs[j];
        atomicAdd(&s_loc[rc.y * 2 + h], expf(lrelu(als[rc.x * 2 + h] + ad_n)));
    }
    __syncthreads();
    if (t < NR * HH) s_loc[t] = 1.f / (s_loc[t] + 1e-16f);
    __syncthreads();
    float rsum = s_loc[0 + h] + s_loc[2 + h] + s_loc[4 + h] +
                 s_loc[6 + h] + s_loc[8 + h] + s_loc[10 + h];
    float coef = els * rsum;
    float a0[4], a1[4];
    uint2 sv = *(const uint2*)&xs[(size_t)n * 256 + t * 4];
    a0[0] = coef * __uint_as_float(sv.x << 16)          + 6.f * bias[t * 4 + 0];
    a0[1] = coef * __uint_as_float(sv.x & 0xffff0000u)  + 6.f * bias[t * 4 + 1];
    a0[2] = coef * __uint_as_float(sv.y << 16)          + 6.f * bias[t * 4 + 2];
    a0[3] = coef * __uint_as_float(sv.y & 0xffff0000u)  + 6.f * bias[t * 4 + 3];
#pragma unroll
    for (int q = 0; q < 4; ++q) a1[q] = 0.f;
    int j = beg;
    for (; j + 1 < end; j += 2) {
        int2 r0 = recs[j], r1 = recs[j + 1];
        uint2 v0 = *(const uint2*)&xs[(size_t)r0.x * 256 + t * 4];
        uint2 v1 = *(const uint2*)&xs[(size_t)r1.x * 256 + t * 4];
        float l0 = lrelu(als[r0.x * 2 + h] + ad_n);
        float l1 = lrelu(als[r1.x * 2 + h] + ad_n);
        float al0 = expf(l0) * s_loc[r0.y * 2 + h];
        float al1 = expf(l1) * s_loc[r1.y * 2 + h];
        a0[0] = fmaf(al0, __uint_as_float(v0.x << 16), a0[0]);
        a0[1] = fmaf(al0, __uint_as_float(v0.x & 0xffff0000u), a0[1]);
        a0[2] = fmaf(al0, __uint_as_float(v0.y << 16), a0[2]);
        a0[3] = fmaf(al0, __uint_as_float(v0.y & 0xffff0000u), a0[3]);
        a1[0] = fmaf(al1, __uint_as_float(v1.x << 16), a1[0]);
        a1[1] = fmaf(al1, __uint_as_float(v1.x & 0xffff0000u), a1[1]);
        a1[2] = fmaf(al1, __uint_as_float(v1.y << 16), a1[2]);
        a1[3] = fmaf(al1, __uint_as_float(v1.y & 0xffff0000u), a1[3]);
    }
    if (j < end) {
        int2 r0 = recs[j];
        uint2 v0 = *(const uint2*)&xs[(size_t)r0.x * 256 + t * 4];
        float l0 = lrelu(als[r0.x * 2 + h] + ad_n);
        float al0 = expf(l0) * s_loc[r0.y * 2 + h];
        a0[0] = fmaf(al0, __uint_as_float(v0.x << 16), a0[0]);
        a0[1] = fmaf(al0, __uint_as_float(v0.x & 0xffff0000u), a0[1]);
        a0[2] = fmaf(al0, __uint_as_float(v0.y << 16), a0[2]);
        a0[3] = fmaf(al0, __uint_as_float(v0.y & 0xffff0000u), a0[3]);
    }
    float4 o = make_float4(a0[0] + a1[0], a0[1] + a1[1], a0[2] + a1[2], a0[3] + a1[3]);
    *(float4*)&out[(size_t)n * 256 + t * 4] = o;
}

extern "C" void kernel_launch(void* const* d_in, const int* in_sizes, int n_in,
                              void* d_out, int out_size, void* d_ws, size_t ws_size,
                              hipStream_t stream) {
    const float* x = (const float*)d_in[0];
    EdgePtrs ep;
    for (int r = 0; r < NR; ++r) ep.e[r] = (const int*)d_in[1 + r];
    const float* W1s = (const float*)d_in[7];
    const float* W1d = (const float*)d_in[8];
    const float* a1s = (const float*)d_in[9];
    const float* a1d = (const float*)d_in[10];
    const float* b1  = (const float*)d_in[11];
    const float* W2s = (const float*)d_in[12];
    const float* W2d = (const float*)d_in[13];
    const float* a2s = (const float*)d_in[14];
    const float* a2d = (const float*)d_in[15];
    const float* b2  = (const float*)d_in[16];
    float* out = (float*)d_out;

    char* base = (char*)d_ws;
    size_t off = 0;
    auto take = [&](size_t nbytes) -> void* {
        void* p = base + off;
        off = (off + nbytes + 255) & ~(size_t)255;
        return p;
    };
    unsigned short* xb   = (unsigned short*)take((size_t)NN * 512 * 2);
    unsigned short* xs1b = (unsigned short*)take((size_t)NN * 1024 * 2);
    unsigned short* h1b  = (unsigned short*)take((size_t)NN * 1024 * 2);
    unsigned short* xs2b = xs1b;  // reuse (xs1 dead after L1 aggregate)
    unsigned short* Wb1  = (unsigned short*)take((size_t)1024 * 512 * 2);
    unsigned short* Wb2  = (unsigned short*)take((size_t)256 * 1024 * 2);
    // as1, ad1, as2, ad2, count contiguous -> single memset zeroes all
    float* as1   = (float*)take((size_t)NN * HH * 4);
    float* ad1   = (float*)take((size_t)NN * HH * 4);
    float* as2   = (float*)take((size_t)NN * HH * 4);
    float* ad2   = (float*)take((size_t)NN * HH * 4);
    int* count   = (int*)take((size_t)NN * 4);
    int* offs    = (int*)take((size_t)(NN + 1) * 4);
    int* cursor  = (int*)take((size_t)NN * 4);
    int2* recs   = (int2*)take((size_t)NR * EE * 8);
    float* wtd1  = (float*)take((size_t)HH * 512 * 4);
    float* wts2  = (float*)take((size_t)HH * 1024 * 4);
    float* wtd2  = (float*)take((size_t)HH * 1024 * 4);

    const int EB = (NR * EE + 255) / 256;
    const int NX = NN * 512, NW1 = 1024 * 512, NW2 = 256 * 1024;
    const int FB = ((NX + NW1 + NW2) / 4 + 255) / 256;

    // zero as1, ad1, as2, ad2, count in one shot
    hipMemsetAsync(as1, 0, (size_t)4 * NN * HH * 4 + (size_t)NN * 4, stream);

    // ---------------- Layer 1: K=512, C=512, Nout=1024 ----------------
    {
        const int K = 512, Nout = 1024;
        // bf16 convert (x, W1s, W2s) + CSR dst histogram, one launch
        f2b_count<<<FB + EB, 256, 0, stream>>>(x, xb, NX, W1s, Wb1, NW1, W2s, Wb2, NW2,
                                               FB, ep, count);
        // al_src fused into gemm epilogue (uses xs = x@W1s^T)
        gemm_nt_mfma<128, true><<<dim3(Nout / 128, (NN + 127) / 128), 256, 0, stream>>>(
            xb, Wb1, xs1b, NN, Nout, K, a1s, as1);
        // all 3 folds: wtd1 (L1 dst), wts2/wtd2 (L2)
        fold_all<<<dim3(16, HH, 3), 256, 0, stream>>>(W1d, a1d, wtd1,
                                                      W2s, a2s, wts2, W2d, a2d, wtd2);
        // al_dst = x . wtd1  +  coalesced CSR exclusive scan (last block)
        al_dst_scan<<<(NN + 3) / 4 + 1, 256, 0, stream>>>(xb, wtd1, K, ad1,
                                                          count, offs, cursor);
        scatter_static<<<EB, 256, 0, stream>>>(ep, cursor, recs);
        aggregate_l1f<<<NN * 2, 64, 0, stream>>>(xs1b, recs, offs, as1, ad1,
                                                 b1, wts2, wtd2, as2, ad2, h1b);
    }
    // ---------------- Layer 2: K=1024, C=128, Nout=256 ----------------
    {
        const int K = 1024, Nout = 256;
        gemm_nt_mfma<64, false><<<dim3(Nout / 64, (NN + 127) / 128), 256, 0, stream>>>(
            h1b, Wb2, xs2b, NN, Nout, K, nullptr, nullptr);
        aggregate_l2<<<NN, 64, 0, stream>>>(xs2b, recs, offs, as2, ad2, b2, out);
    }
}

// Round 15
// 409.137 us; speedup vs baseline: 1.1241x; 1.1241x over previous
//
#include <hip/hip_runtime.h>
#include <cstddef>

#define NN 20000
#define EE 100000
#define NR 6
#define HH 2
#define NEG 0.2f
#define NB ((NN + 1023) / 1024)

struct EdgePtrs { const int* e[NR]; };

typedef __attribute__((ext_vector_type(8))) short bf16x8;
typedef __attribute__((ext_vector_type(4))) float f32x4;

__device__ __forceinline__ unsigned short rnebf(float f) {
    unsigned u = __float_as_uint(f);
    return (unsigned short)((u + 0x7fffu + ((u >> 16) & 1u)) >> 16);
}
__device__ __forceinline__ void unpack8(uint4 v, float* f) {
    f[0] = __uint_as_float(v.x << 16); f[1] = __uint_as_float(v.x & 0xffff0000u);
    f[2] = __uint_as_float(v.y << 16); f[3] = __uint_as_float(v.y & 0xffff0000u);
    f[4] = __uint_as_float(v.z << 16); f[5] = __uint_as_float(v.z & 0xffff0000u);
    f[6] = __uint_as_float(v.w << 16); f[7] = __uint_as_float(v.w & 0xffff0000u);
}
__device__ __forceinline__ unsigned pack2(float a, float b) {
    return (unsigned)rnebf(a) | ((unsigned)rnebf(b) << 16);
}
__device__ __forceinline__ float lrelu(float l) { return l > 0.f ? l : NEG * l; }
__device__ __forceinline__ void glld16(unsigned short* lds, const void* g) {
    __builtin_amdgcn_global_load_lds(
        (const __attribute__((address_space(1))) unsigned int*)g,
        (__attribute__((address_space(3))) unsigned int*)lds, 16, 0, 0);
}

// fp32->bf16 of x, W1, W2  PLUS  CSR dst-histogram, one launch (block-role split)
__global__ void f2b_count(const float* __restrict__ x, unsigned short* __restrict__ xb, int nx,
                          const float* __restrict__ w1, unsigned short* __restrict__ wb1, int nw1,
                          const float* __restrict__ w2, unsigned short* __restrict__ wb2, int nw2,
                          int fb, EdgePtrs ep, int* __restrict__ count) {
    int b = blockIdx.x;
    if (b >= fb) {
        int i = (b - fb) * 256 + threadIdx.x;
        if (i < NR * EE) {
            int r = i / EE, ei = i - r * EE;
            atomicAdd(&count[ep.e[r][EE + ei]], 1);
        }
        return;
    }
    int i = (b * 256 + threadIdx.x) * 4;
    const float* in; unsigned short* out; int k;
    if (i < nx) { in = x; out = xb; k = i; }
    else if (i < nx + nw1) { in = w1; out = wb1; k = i - nx; }
    else if (i < nx + nw1 + nw2) { in = w2; out = wb2; k = i - nx - nw1; }
    else return;
    float4 v = *(const float4*)&in[k];
    unsigned short o[4] = {rnebf(v.x), rnebf(v.y), rnebf(v.z), rnebf(v.w)};
    *(uint2*)&out[k] = *(uint2*)o;
}

// all three attention-vector folds in one launch
__global__ void fold_all(const float* __restrict__ W1d, const float* __restrict__ a1d,
                         float* __restrict__ wtd1,
                         const float* __restrict__ W2s, const float* __restrict__ a2s,
                         float* __restrict__ wts2,
                         const float* __restrict__ W2d, const float* __restrict__ a2d,
                         float* __restrict__ wtd2) {
    __shared__ float red[256];
    const float *W, *a; float* wt; int C, K;
    if (blockIdx.z == 0)      { W = W1d; a = a1d; wt = wtd1; C = 512; K = 512; }
    else if (blockIdx.z == 1) { W = W2s; a = a2s; wt = wts2; C = 128; K = 1024; }
    else                      { W = W2d; a = a2d; wt = wtd2; C = 128; K = 1024; }
    int h = blockIdx.y;
    int k = blockIdx.x * 64 + (threadIdx.x & 63);
    if (k >= K) return;   // block-uniform (K multiple of 64)
    int cp = threadIdx.x >> 6;
    float acc = 0.f;
    for (int c = cp; c < C; c += 4)
        acc = fmaf(a[h * C + c], W[(size_t)(h * C + c) * K + k], acc);
    red[threadIdx.x] = acc;
    __syncthreads();
    if (cp == 0) {
        wt[h * K + k] = red[threadIdx.x] + red[threadIdx.x + 64] +
                        red[threadIdx.x + 128] + red[threadIdx.x + 192];
    }
}

// C[M][Nn] = A[M][K] @ B[Nn][K]^T, bf16 in/out, fp32 accum (MFMA 16x16x32).
// FUSEAL: per-row dot of the OUTPUT with a1_src (al_src = xs . a_src).
template <int BN, bool FUSEAL>
__global__ __launch_bounds__(256) void gemm_nt_mfma(
    const unsigned short* __restrict__ A, const unsigned short* __restrict__ B,
    unsigned short* __restrict__ C, int M, int Nn, int K,
    const float* __restrict__ a1s, float* __restrict__ as1) {
    constexpr int NF = BN / 32;
    __shared__ unsigned short As[128 * 32];
    __shared__ unsigned short Bs[BN * 32];
    const int tid = threadIdx.x;
    const int lane = tid & 63;
    const int wave = tid >> 6;
    const int wr = wave >> 1, wc = wave & 1;
    const int row0 = blockIdx.y * 128, col0 = blockIdx.x * BN;

    f32x4 acc[4][NF];
#pragma unroll
    for (int i = 0; i < 4; ++i)
#pragma unroll
        for (int j = 0; j < NF; ++j) acc[i][j] = (f32x4){0.f, 0.f, 0.f, 0.f};

    const int srow = tid >> 2;
    const int slot = tid & 3;
    const int sw = ((slot ^ (srow & 3)) << 4);
    int ar0 = row0 + srow;        if (ar0 >= M) ar0 = M - 1;
    int ar1 = row0 + srow + 64;   if (ar1 >= M) ar1 = M - 1;
    const int br0 = col0 + srow;
    const int br1 = col0 + srow + 64;

    const int q = lane >> 4;
    for (int k0 = 0; k0 < K; k0 += 32) {
        glld16(As + tid * 8,        (const char*)A + ((size_t)ar0 * K + k0) * 2 + sw);
        glld16(As + tid * 8 + 2048, (const char*)A + ((size_t)ar1 * K + k0) * 2 + sw);
        glld16(Bs + tid * 8,        (const char*)B + ((size_t)br0 * K + k0) * 2 + sw);
        if (BN == 128)
            glld16(Bs + tid * 8 + 2048, (const char*)B + ((size_t)br1 * K + k0) * 2 + sw);
        __syncthreads();
        bf16x8 af[4], bfr[NF];
#pragma unroll
        for (int m = 0; m < 4; ++m) {
            int r = wr * 64 + m * 16 + (lane & 15);
            af[m] = *(const bf16x8*)&As[r * 32 + ((q ^ (r & 3)) << 3)];
        }
#pragma unroll
        for (int nI = 0; nI < NF; ++nI) {
            int c = wc * (BN / 2) + nI * 16 + (lane & 15);
            bfr[nI] = *(const bf16x8*)&Bs[c * 32 + ((q ^ (c & 3)) << 3)];
        }
#pragma unroll
        for (int m = 0; m < 4; ++m)
#pragma unroll
            for (int nI = 0; nI < NF; ++nI)
                acc[m][nI] = __builtin_amdgcn_mfma_f32_16x16x32_bf16(af[m], bfr[nI], acc[m][nI], 0, 0, 0);
        __syncthreads();
    }
    const int crow = (lane >> 4) * 4;
    const int ccol = lane & 15;
#pragma unroll
    for (int m = 0; m < 4; ++m)
#pragma unroll
        for (int nI = 0; nI < NF; ++nI)
#pragma unroll
            for (int j = 0; j < 4; ++j) {
                int r = row0 + wr * 64 + m * 16 + crow + j;
                int c = col0 + wc * (BN / 2) + nI * 16 + ccol;
                if (r < M) C[(size_t)r * Nn + c] = rnebf(acc[m][nI][j]);
            }
    if constexpr (FUSEAL) {
        const int hb = col0 >> 9;                   // C1 = 512
        float aS[NF];
#pragma unroll
        for (int nI = 0; nI < NF; ++nI) {
            int gc = col0 + wc * (BN / 2) + nI * 16 + ccol;
            aS[nI] = a1s[hb * 512 + (gc & 511)];
        }
#pragma unroll
        for (int m = 0; m < 4; ++m)
#pragma unroll
            for (int j = 0; j < 4; ++j) {
                float ps = 0.f;
#pragma unroll
                for (int nI = 0; nI < NF; ++nI)
                    ps = fmaf(acc[m][nI][j], aS[nI], ps);
                for (int o = 1; o < 16; o <<= 1)
                    ps += __shfl_xor(ps, o);
                if ((lane & 15) == 0) {
                    int r = row0 + wr * 64 + m * 16 + crow + j;
                    if (r < M) atomicAdd(&as1[r * 2 + hb], ps);
                }
            }
    }
}

// wave-per-node: ad[n][h] = sum_k x[n,k] * wtd[h,k]  (dst logits only)
__global__ void al_dst_w(const unsigned short* __restrict__ x, const float* __restrict__ wtd,
                         int K, float* __restrict__ ad) {
    int lane = threadIdx.x & 63;
    int n = blockIdx.x * 4 + (threadIdx.x >> 6);
    if (n >= NN) return;
    float d0 = 0.f, d1 = 0.f;
    for (int k0 = 0; k0 < K; k0 += 512) {
        int k = k0 + lane * 8;
        uint4 xv = *(const uint4*)&x[(size_t)n * K + k];
        float xf[8];
        unpack8(xv, xf);
        float4 wda = *(const float4*)&wtd[k],     wdb = *(const float4*)&wtd[k + 4];
        float4 wdc = *(const float4*)&wtd[K + k], wdd = *(const float4*)&wtd[K + k + 4];
        d0 = fmaf(xf[0], wda.x, d0); d0 = fmaf(xf[1], wda.y, d0);
        d0 = fmaf(xf[2], wda.z, d0); d0 = fmaf(xf[3], wda.w, d0);
        d0 = fmaf(xf[4], wdb.x, d0); d0 = fmaf(xf[5], wdb.y, d0);
        d0 = fmaf(xf[6], wdb.z, d0); d0 = fmaf(xf[7], wdb.w, d0);
        d1 = fmaf(xf[0], wdc.x, d1); d1 = fmaf(xf[1], wdc.y, d1);
        d1 = fmaf(xf[2], wdc.z, d1); d1 = fmaf(xf[3], wdc.w, d1);
        d1 = fmaf(xf[4], wdd.x, d1); d1 = fmaf(xf[5], wdd.y, d1);
        d1 = fmaf(xf[6], wdd.z, d1); d1 = fmaf(xf[7], wdd.w, d1);
    }
    for (int o = 32; o > 0; o >>= 1) {
        d0 += __shfl_down(d0, o); d1 += __shfl_down(d1, o);
    }
    if (lane == 0) {
        ad[n * 2 + 0] = d0;
        ad[n * 2 + 1] = d1;
    }
}

// --- 3-stage parallel exclusive scan of count[NN] -> offs, cursor ---
__global__ void block_sum(const int* __restrict__ count, int* __restrict__ bsum) {
    int base = blockIdx.x * 1024;
    int tid = threadIdx.x;
    int s = 0;
    for (int i = tid; i < 1024; i += 256) {
        int idx = base + i;
        s += (idx < NN) ? count[idx] : 0;
    }
    for (int o = 32; o > 0; o >>= 1) s += __shfl_down(s, o);
    __shared__ int ws[4];
    if ((tid & 63) == 0) ws[tid >> 6] = s;
    __syncthreads();
    if (tid == 0) bsum[blockIdx.x] = ws[0] + ws[1] + ws[2] + ws[3];
}

__global__ void scan_small(const int* __restrict__ bsum, int* __restrict__ bbase,
                           int* __restrict__ offs) {
    if (threadIdx.x == 0) {
        int run = 0;
        for (int i = 0; i < NB; ++i) { bbase[i] = run; run += bsum[i]; }
        offs[NN] = run;
    }
}

__global__ void scan_blocks(const int* __restrict__ count, const int* __restrict__ bbase,
                            int* __restrict__ offs, int* __restrict__ cursor) {
    __shared__ int wsum[16];
    __shared__ int wbase[16];
    int tid = threadIdx.x;
    int lane = tid & 63;
    int wid = tid >> 6;
    int idx = blockIdx.x * 1024 + tid;
    int v = (idx < NN) ? count[idx] : 0;
    int xv = v;
    for (int d = 1; d < 64; d <<= 1) {
        int t = __shfl_up(xv, d);
        if (lane >= d) xv += t;
    }
    if (lane == 63) wsum[wid] = xv;
    __syncthreads();
    if (wid == 0 && lane < 16) {
        int wv = wsum[lane];
        int wx = wv;
        for (int d = 1; d < 16; d <<= 1) {
            int t = __shfl_up(wx, d);
            if (lane >= d) wx += t;
        }
        wbase[lane] = wx - wv;
    }
    __syncthreads();
    int excl = xv - v + wbase[wid] + bbase[blockIdx.x];
    if (idx < NN) { offs[idx] = excl; cursor[idx] = excl; }
}

// static CSR scatter (once): record = (src, relation)
__global__ void scatter_static(EdgePtrs ep, int* __restrict__ cursor, int2* __restrict__ recs) {
    int i = blockIdx.x * 256 + threadIdx.x;
    if (i >= NR * EE) return;
    int r = i / EE, ei = i - r * EE;
    int sN = ep.e[r][ei];
    int d = ep.e[r][EE + ei];
    int slot = atomicAdd(&cursor[d], 1);
    recs[slot] = make_int2(sN, r);
}

// L1 aggregate: in-block softmax denominators (LDS), inline-alpha,
// fused L2-al partial dots. 2 blocks/node (one per head), 64 thr x 8 ch.
__global__ __launch_bounds__(64) void aggregate_l1f(
    const unsigned short* __restrict__ xs, const int2* __restrict__ recs,
    const int* __restrict__ offs,
    const float* __restrict__ als, const float* __restrict__ ald,
    const float* __restrict__ bias,
    const float* __restrict__ wts2, const float* __restrict__ wtd2,
    float* __restrict__ as2, float* __restrict__ ad2,
    unsigned short* __restrict__ out) {
    __shared__ float s_loc[NR];
    int bid = blockIdx.x;
    int n = bid >> 1;
    int half = bid & 1;
    int t = threadIdx.x;
    int c0 = half * 512 + t * 8;
    float ad_n = ald[n * 2 + half];
    float els = expf(lrelu(als[n * 2 + half] + ad_n));  // self-loop term
    if (t < NR) s_loc[t] = els;
    __syncthreads();
    int beg = offs[n], end = offs[n + 1];
    for (int j = beg + t; j < end; j += 64) {
        int2 rc = recs[j];
        atomicAdd(&s_loc[rc.y], expf(lrelu(als[rc.x * 2 + half] + ad_n)));
    }
    __syncthreads();
    if (t < NR) s_loc[t] = 1.f / (s_loc[t] + 1e-16f);
    __syncthreads();
    float rsum = s_loc[0] + s_loc[1] + s_loc[2] + s_loc[3] + s_loc[4] + s_loc[5];
    float coef = els * rsum;
    float a0[8], a1[8], f[8];
    uint4 sv = *(const uint4*)&xs[(size_t)n * 1024 + c0];
    unpack8(sv, f);
#pragma unroll
    for (int j = 0; j < 8; ++j) {
        a0[j] = coef * f[j] + 6.f * bias[c0 + j];
        a1[j] = 0.f;
    }
    int j = beg;
    for (; j + 1 < end; j += 2) {
        int2 r0 = recs[j], r1 = recs[j + 1];
        uint4 v0 = *(const uint4*)&xs[(size_t)r0.x * 1024 + c0];
        uint4 v1 = *(const uint4*)&xs[(size_t)r1.x * 1024 + c0];
        float l0 = lrelu(als[r0.x * 2 + half] + ad_n);
        float l1 = lrelu(als[r1.x * 2 + half] + ad_n);
        float al0 = expf(l0) * s_loc[r0.y];
        float al1 = expf(l1) * s_loc[r1.y];
        unpack8(v0, f);
#pragma unroll
        for (int q = 0; q < 8; ++q) a0[q] = fmaf(al0, f[q], a0[q]);
        unpack8(v1, f);
#pragma unroll
        for (int q = 0; q < 8; ++q) a1[q] = fmaf(al1, f[q], a1[q]);
    }
    if (j < end) {
        int2 r0 = recs[j];
        uint4 v0 = *(const uint4*)&xs[(size_t)r0.x * 1024 + c0];
        float l0 = lrelu(als[r0.x * 2 + half] + ad_n);
        float al0 = expf(l0) * s_loc[r0.y];
        unpack8(v0, f);
#pragma unroll
        for (int q = 0; q < 8; ++q) a0[q] = fmaf(al0, f[q], a0[q]);
    }
    float rr[8];
#pragma unroll
    for (int q = 0; q < 8; ++q) rr[q] = fmaxf(a0[q] + a1[q], 0.f);
    uint4 o;
    o.x = pack2(rr[0], rr[1]); o.y = pack2(rr[2], rr[3]);
    o.z = pack2(rr[4], rr[5]); o.w = pack2(rr[6], rr[7]);
    *(uint4*)&out[(size_t)n * 1024 + c0] = o;
    // fused L2 attention-logit partial dots over this 8-channel slice
    float ps0, ps1, pd0, pd1;
    float4 wsa = *(const float4*)&wts2[c0],        wsb = *(const float4*)&wts2[c0 + 4];
    float4 wsc = *(const float4*)&wts2[1024 + c0], wsd = *(const float4*)&wts2[1024 + c0 + 4];
    float4 wda = *(const float4*)&wtd2[c0],        wdb = *(const float4*)&wtd2[c0 + 4];
    float4 wdc = *(const float4*)&wtd2[1024 + c0], wdd = *(const float4*)&wtd2[1024 + c0 + 4];
    ps0 = rr[0]*wsa.x + rr[1]*wsa.y + rr[2]*wsa.z + rr[3]*wsa.w
        + rr[4]*wsb.x + rr[5]*wsb.y + rr[6]*wsb.z + rr[7]*wsb.w;
    ps1 = rr[0]*wsc.x + rr[1]*wsc.y + rr[2]*wsc.z + rr[3]*wsc.w
        + rr[4]*wsd.x + rr[5]*wsd.y + rr[6]*wsd.z + rr[7]*wsd.w;
    pd0 = rr[0]*wda.x + rr[1]*wda.y + rr[2]*wda.z + rr[3]*wda.w
        + rr[4]*wdb.x + rr[5]*wdb.y + rr[6]*wdb.z + rr[7]*wdb.w;
    pd1 = rr[0]*wdc.x + rr[1]*wdc.y + rr[2]*wdc.z + rr[3]*wdc.w
        + rr[4]*wdd.x + rr[5]*wdd.y + rr[6]*wdd.z + rr[7]*wdd.w;
    for (int o2 = 32; o2 > 0; o2 >>= 1) {
        ps0 += __shfl_down(ps0, o2); ps1 += __shfl_down(ps1, o2);
        pd0 += __shfl_down(pd0, o2); pd1 += __shfl_down(pd1, o2);
    }
    if (t == 0) {
        atomicAdd(&as2[n * 2 + 0], ps0);
        atomicAdd(&as2[n * 2 + 1], ps1);
        atomicAdd(&ad2[n * 2 + 0], pd0);
        atomicAdd(&ad2[n * 2 + 1], pd1);
    }
}

// L2 aggregate: in-block denominators (both heads), inline-alpha. 64 thr x 4 ch.
__global__ __launch_bounds__(64) void aggregate_l2(
    const unsigned short* __restrict__ xs, const int2* __restrict__ recs,
    const int* __restrict__ offs,
    const float* __restrict__ als, const float* __restrict__ ald,
    const float* __restrict__ bias, float* __restrict__ out) {
    __shared__ float s_loc[NR * HH];   // [r][h]
    int n = blockIdx.x;
    int t = threadIdx.x;
    int h = t >> 5;
    float ad_n = ald[n * 2 + h];
    float els = expf(lrelu(als[n * 2 + h] + ad_n));
    if (t < NR * HH) s_loc[t] = expf(lrelu(als[n * 2 + (t & 1)] + ald[n * 2 + (t & 1)]));
    __syncthreads();
    int beg = offs[n], end = offs[n + 1];
    for (int j = beg + (t & 31); j < end; j += 32) {
        int2 rc = recs[j];
        atomicAdd(&s_loc[rc.y * 2 + h], expf(lrelu(als[rc.x * 2 + h] + ad_n)));
    }
    __syncthreads();
    if (t < NR * HH) s_loc[t] = 1.f / (s_loc[t] + 1e-16f);
    __syncthreads();
    float rsum = s_loc[0 + h] + s_loc[2 + h] + s_loc[4 + h] +
                 s_loc[6 + h] + s_loc[8 + h] + s_loc[10 + h];
    float coef = els * rsum;
    float a0[4], a1[4];
    uint2 sv = *(const uint2*)&xs[(size_t)n * 256 + t * 4];
    a0[0] = coef * __uint_as_float(sv.x << 16)          + 6.f * bias[t * 4 + 0];
    a0[1] = coef * __uint_as_float(sv.x & 0xffff0000u)  + 6.f * bias[t * 4 + 1];
    a0[2] = coef * __uint_as_float(sv.y << 16)          + 6.f * bias[t * 4 + 2];
    a0[3] = coef * __uint_as_float(sv.y & 0xffff0000u)  + 6.f * bias[t * 4 + 3];
#pragma unroll
    for (int q = 0; q < 4; ++q) a1[q] = 0.f;
    int j = beg;
    for (; j + 1 < end; j += 2) {
        int2 r0 = recs[j], r1 = recs[j + 1];
        uint2 v0 = *(const uint2*)&xs[(size_t)r0.x * 256 + t * 4];
        uint2 v1 = *(const uint2*)&xs[(size_t)r1.x * 256 + t * 4];
        float l0 = lrelu(als[r0.x * 2 + h] + ad_n);
        float l1 = lrelu(als[r1.x * 2 + h] + ad_n);
        float al0 = expf(l0) * s_loc[r0.y * 2 + h];
        float al1 = expf(l1) * s_loc[r1.y * 2 + h];
        a0[0] = fmaf(al0, __uint_as_float(v0.x << 16), a0[0]);
        a0[1] = fmaf(al0, __uint_as_float(v0.x & 0xffff0000u), a0[1]);
        a0[2] = fmaf(al0, __uint_as_float(v0.y << 16), a0[2]);
        a0[3] = fmaf(al0, __uint_as_float(v0.y & 0xffff0000u), a0[3]);
        a1[0] = fmaf(al1, __uint_as_float(v1.x << 16), a1[0]);
        a1[1] = fmaf(al1, __uint_as_float(v1.x & 0xffff0000u), a1[1]);
        a1[2] = fmaf(al1, __uint_as_float(v1.y << 16), a1[2]);
        a1[3] = fmaf(al1, __uint_as_float(v1.y & 0xffff0000u), a1[3]);
    }
    if (j < end) {
        int2 r0 = recs[j];
        uint2 v0 = *(const uint2*)&xs[(size_t)r0.x * 256 + t * 4];
        float l0 = lrelu(als[r0.x * 2 + h] + ad_n);
        float al0 = expf(l0) * s_loc[r0.y * 2 + h];
        a0[0] = fmaf(al0, __uint_as_float(v0.x << 16), a0[0]);
        a0[1] = fmaf(al0, __uint_as_float(v0.x & 0xffff0000u), a0[1]);
        a0[2] = fmaf(al0, __uint_as_float(v0.y << 16), a0[2]);
        a0[3] = fmaf(al0, __uint_as_float(v0.y & 0xffff0000u), a0[3]);
    }
    float4 o = make_float4(a0[0] + a1[0], a0[1] + a1[1], a0[2] + a1[2], a0[3] + a1[3]);
    *(float4*)&out[(size_t)n * 256 + t * 4] = o;
}

extern "C" void kernel_launch(void* const* d_in, const int* in_sizes, int n_in,
                              void* d_out, int out_size, void* d_ws, size_t ws_size,
                              hipStream_t stream) {
    const float* x = (const float*)d_in[0];
    EdgePtrs ep;
    for (int r = 0; r < NR; ++r) ep.e[r] = (const int*)d_in[1 + r];
    const float* W1s = (const float*)d_in[7];
    const float* W1d = (const float*)d_in[8];
    const float* a1s = (const float*)d_in[9];
    const float* a1d = (const float*)d_in[10];
    const float* b1  = (const float*)d_in[11];
    const float* W2s = (const float*)d_in[12];
    const float* W2d = (const float*)d_in[13];
    const float* a2s = (const float*)d_in[14];
    const float* a2d = (const float*)d_in[15];
    const float* b2  = (const float*)d_in[16];
    float* out = (float*)d_out;

    char* base = (char*)d_ws;
    size_t off = 0;
    auto take = [&](size_t nbytes) -> void* {
        void* p = base + off;
        off = (off + nbytes + 255) & ~(size_t)255;
        return p;
    };
    unsigned short* xb   = (unsigned short*)take((size_t)NN * 512 * 2);
    unsigned short* xs1b = (unsigned short*)take((size_t)NN * 1024 * 2);
    unsigned short* h1b  = (unsigned short*)take((size_t)NN * 1024 * 2);
    unsigned short* xs2b = xs1b;  // reuse (xs1 dead after L1 aggregate)
    unsigned short* Wb1  = (unsigned short*)take((size_t)1024 * 512 * 2);
    unsigned short* Wb2  = (unsigned short*)take((size_t)256 * 1024 * 2);
    // as1, ad1, as2, ad2, count contiguous -> single memset zeroes all
    float* as1   = (float*)take((size_t)NN * HH * 4);
    float* ad1   = (float*)take((size_t)NN * HH * 4);
    float* as2   = (float*)take((size_t)NN * HH * 4);
    float* ad2   = (float*)take((size_t)NN * HH * 4);
    int* count   = (int*)take((size_t)NN * 4);
    int* offs    = (int*)take((size_t)(NN + 1) * 4);
    int* cursor  = (int*)take((size_t)NN * 4);
    int2* recs   = (int2*)take((size_t)NR * EE * 8);
    float* wtd1  = (float*)take((size_t)HH * 512 * 4);
    float* wts2  = (float*)take((size_t)HH * 1024 * 4);
    float* wtd2  = (float*)take((size_t)HH * 1024 * 4);
    int* bsum    = (int*)take((size_t)NB * 4);
    int* bbase   = (int*)take((size_t)NB * 4);

    const int EB = (NR * EE + 255) / 256;
    const int NX = NN * 512, NW1 = 1024 * 512, NW2 = 256 * 1024;
    const int FB = ((NX + NW1 + NW2) / 4 + 255) / 256;

    // zero as1, ad1, as2, ad2, count in one shot
    hipMemsetAsync(as1, 0, (size_t)4 * NN * HH * 4 + (size_t)NN * 4, stream);

    // ---------------- Layer 1: K=512, C=512, Nout=1024 ----------------
    {
        const int K = 512, Nout = 1024;
        // bf16 convert (x, W1s, W2s) + CSR dst histogram, one launch
        f2b_count<<<FB + EB, 256, 0, stream>>>(x, xb, NX, W1s, Wb1, NW1, W2s, Wb2, NW2,
                                               FB, ep, count);
        // al_src fused into gemm epilogue (uses xs = x@W1s^T)
        gemm_nt_mfma<128, true><<<dim3(Nout / 128, (NN + 127) / 128), 256, 0, stream>>>(
            xb, Wb1, xs1b, NN, Nout, K, a1s, as1);
        // all 3 folds: wtd1 (L1 dst), wts2/wtd2 (L2)
        fold_all<<<dim3(16, HH, 3), 256, 0, stream>>>(W1d, a1d, wtd1,
                                                      W2s, a2s, wts2, W2d, a2d, wtd2);
        // al_dst = x . wtd1
        al_dst_w<<<(NN + 3) / 4, 256, 0, stream>>>(xb, wtd1, K, ad1);
        // parallel 3-stage CSR scan
        block_sum<<<NB, 256, 0, stream>>>(count, bsum);
        scan_small<<<1, 64, 0, stream>>>(bsum, bbase, offs);
        scan_blocks<<<NB, 1024, 0, stream>>>(count, bbase, offs, cursor);
        scatter_static<<<EB, 256, 0, stream>>>(ep, cursor, recs);
        aggregate_l1f<<<NN * 2, 64, 0, stream>>>(xs1b, recs, offs, as1, ad1,
                                                 b1, wts2, wtd2, as2, ad2, h1b);
    }
    // ---------------- Layer 2: K=1024, C=128, Nout=256 ----------------
    {
        const int K = 1024, Nout = 256;
        gemm_nt_mfma<64, false><<<dim3(Nout / 64, (NN + 127) / 128), 256, 0, stream>>>(
            h1b, Wb2, xs2b, NN, Nout, K, nullptr, nullptr);
        aggregate_l2<<<NN, 64, 0, stream>>>(xs2b, recs, offs, as2, ad2, b2, out);
    }
}